// Round 11
// baseline (112.828 us; speedup 1.0000x reference)
//
#include <hip/hip_runtime.h>

// Problem constants (from reference)
constexpr int L  = 250;   // layers
constexpr int T  = 600;   // traces
constexpr int A  = 30;    // angles

typedef _Float16 h8  __attribute__((ext_vector_type(8)));   // MFMA A/B frag (4 VGPR)
typedef float    f4  __attribute__((ext_vector_type(4)));   // MFMA C/D frag
// 8-B-aligned float4 (odd wm rows are 1000 B apart); dwordx4 needs 4-B HW align
typedef float    f4u __attribute__((ext_vector_type(4), aligned(8)));

// refT LDS row stride (halfs): 264 = 256+8 -> 16-B aligned rows, 2-way-free banks
constexpr int RT_LD = 264;

constexpr int PFD = 4;    // K-steps whose A-fragments are prefetched pre-phase-1

// ---------------- R25: R22 + pre-phase-1 register prefetch of A-frags --------
// Structure ledger (R8..R24): ONLY the R12/R22 family passes. Every failure
// contains one of {ds_write-in-K-loop (R16/17/19/23), producer+d_ws
// (R8-11/21), atomics+grid-split (R24), 512 threads (R14)}. R25 is a pure
// REGISTER delta on R22 (passed, 41.4 us, absmax 0.0039).
//
// Phase-lock model (explains R12=R15=R22 ~41.5 us): phase-1 ~21 us chip VALU
// + A-transport ~20 us TA serialization (256 scattered 64-line wave-instrs
// per block ~80 cyc each) and dur = SUM: grid 600 = 2.34 blk/CU launches in
// one sweep, so all blocks do phase-1 together (TA idle) then K-loop
// together (VALU idle). R15's 2x occupancy: flat -> phase-locked, not
// latency-starved.
//
// Fix: de-phase WITHIN the wave. The A-gather depends on nothing phase-1
// produces -> issue ks 0..3's 16 fragments (f32, 128 VGPR) BEFORE the angle
// loop; their TA occupancy (~10 us/block-share) hides under phase-1's ~9 us
// VALU. K-loop: ks 0..3 from registers (cvt-at-use = R22-identical RNE),
// ks 4..7 verbatim R22 scattered path. Cost: ~175 VGPR -> 2 waves/SIMD ->
// 2 blk/CU (-15% occ; R15 proved occupancy ~free here).
// NO workspace, NO producer, NO in-loop ds_writes, grid 600 x 256.
__global__ __launch_bounds__(256)
void zoep_fused(const float* __restrict__ vp,
                const float* __restrict__ vs,
                const float* __restrict__ rho,
                const float* __restrict__ theta,
                const float* __restrict__ wm,
                float* __restrict__ out)
{
    __shared__ _Float16 refT[32 * RT_LD];   // 16.5 KB: refT[a][k]
    __shared__ float sth_s[32];
    __shared__ float cth_s[32];

    const int tid = threadIdx.x;
    const int t   = blockIdx.x;

    if (tid < 32) {
        const float th = (tid < A) ? theta[tid] : 0.0f;
        sth_s[tid] = sinf(th);
        cth_s[tid] = cosf(th);
    }
    __syncthreads();

    // ---- Phase-1 input loads first (needed in ~10 cycles) -------------------
    const int  k     = tid;
    const bool valid = (k < L - 1);
    const int  kc    = valid ? k : (L - 2);   // clamped: loads always in-bounds

    const float a1 = vp[kc * T + t];          // lane-distinct lines, 1 instr/array
    const float a2 = vp[(kc + 1) * T + t];
    const float b1 = vs[kc * T + t];
    const float b2 = vs[(kc + 1) * T + t];
    const float r1 = rho[kc * T + t];
    const float r2 = rho[(kc + 1) * T + t];

    // ---- Phase-2 geometry + A-fragment PREFETCH (ks 0..PFD-1) ---------------
    // Issued before the phase-1 math: no dependence on refT; registers cross
    // the barrier safely (R20-proven). Cols <= (PFD-1)*32+31 = 127 < 250 ->
    // no clamps (R22 ks<7 path). Rows clamped via wrow (store-masked later).
    const int w    = tid >> 6;       // wave 0..3
    const int lane = tid & 63;
    const int quad = lane >> 4;      // 0..3
    const int n16  = lane & 15;

    const float* wrow[4];
#pragma unroll
    for (int mi = 0; mi < 4; ++mi) {
        const int m = (w * 4 + mi) * 16 + n16;        // logical wm row 0..255
        wrow[mi] = wm + ((m < L) ? m : (L - 1)) * L;
    }

    f4u pf[PFD][4][2];               // 16 frags x 8 f32 = 128 VGPR
#pragma unroll
    for (int ks = 0; ks < PFD; ++ks)
#pragma unroll
        for (int mi = 0; mi < 4; ++mi) {
            pf[ks][mi][0] = *(const f4u*)(wrow[mi] + ks * 32 + quad * 8);
            pf[ks][mi][1] = *(const f4u*)(wrow[mi] + ks * 32 + quad * 8 + 4);
        }

    // ---- Phase 1: thread owns interface k = tid (R12 verbatim math) ---------
    const float ra1  = __builtin_amdgcn_rcpf(a1);
    const float rb1  = r1 * b1, rb2 = r2 * b2;
    const float ra1r = r1 * a1, ra2r = r2 * a2;

#pragma unroll 2
    for (int a = 0; a < A; ++a) {
        const float sth = sth_s[a];           // LDS broadcast (uniform a)
        const float cth = cth_s[a];

        const float p   = sth * ra1;
        const float s2  = p * a2;             // |.| <= 0.84 < 1 (input ranges)
        const float c2  = sqrtf(1.0f - s2 * s2);
        const float sp1 = p * b1;
        const float cp1 = sqrtf(1.0f - sp1 * sp1);
        const float sp2 = p * b2;
        const float cp2 = sqrtf(1.0f - sp2 * sp2);

        const float k1 = 1.0f - 2.0f * sp1 * sp1;
        const float k2 = 1.0f - 2.0f * sp2 * sp2;
        const float q1 = rb1 * k1;
        const float q2 = rb2 * k2;
        const float P1 = ra1r * k1;
        const float P2 = ra2r * k2;
        const float u1 = 2.0f * rb1 * sp1;
        const float u2 = 2.0f * rb2 * sp2;
        const float S1 = u1 * cp1;
        const float S2 = u2 * cp2;
        const float g1 = u1 * cth;
        const float g2 = u2 * c2;

        // M (row-major)
        const float m00 = -sth, m01 = -cp1, m02 = s2,  m03 = cp2;
        const float m10 =  cth, m11 = -sp1, m12 = c2,  m13 = -sp2;
        const float m20 =  g1,  m21 =  q1,  m22 = g2,  m23 = q2;
        const float m30 = -P1,  m31 =  S1,  m32 = P2,  m33 = -S2;

        // 2x2 minors: s* rows{0,1}, c* rows{2,3}
        const float s3v = m01 * m12 - m11 * m02;
        const float s4v = m01 * m13 - m11 * m03;
        const float s5v = m02 * m13 - m12 * m03;
        const float c3v = m21 * m32 - m31 * m22;
        const float c4v = m21 * m33 - m31 * m23;
        const float c5v = m22 * m33 - m32 * m23;
        const float s0v = m00 * m11 - m10 * m01;
        const float s1v = m00 * m12 - m10 * m02;
        const float s2v = m00 * m13 - m10 * m03;
        const float c0v = m20 * m31 - m30 * m21;
        const float c1v = m20 * m32 - m30 * m22;
        const float c2v = m20 * m33 - m30 * m23;

        const float detM = s0v*c5v - s1v*c4v + s2v*c3v
                         + s3v*c2v - s4v*c1v + s5v*c0v;
        const float A0 = m11*c5v - m12*c4v + m13*c3v;   // minor(0,0)
        const float A3 = m21*s5v - m22*s4v + m23*s3v;   // minor(3,0)

        const float num = m00 * A0 - m30 * A3;
        const float res = 1.0f - 2.0f * num * __builtin_amdgcn_rcpf(detM);

        refT[a * RT_LD + k] = (_Float16)(valid ? res : 0.0f);
    }
    // zero pad rows a = 30, 31 (column k)
    refT[30 * RT_LD + k] = (_Float16)0.0f;
    refT[31 * RT_LD + k] = (_Float16)0.0f;
    __syncthreads();

    // ---- Phase 2: MFMA GEMM (R22 layouts, verified) -------------------------
    // A[m=lane&15][k=quad*8+j], B[k=quad*8+j][n=lane&15], C/D[row=quad*4+r][col=n16]
    f4 acc[4][2];
#pragma unroll
    for (int mi = 0; mi < 4; ++mi)
#pragma unroll
        for (int nt = 0; nt < 2; ++nt) acc[mi][nt] = (f4){0.f, 0.f, 0.f, 0.f};

    // ks 0..PFD-1: A-frags from prefetched registers (cvt-at-use, RNE = R22)
#pragma unroll
    for (int ks = 0; ks < PFD; ++ks) {
        const int kofs = ks * 32 + quad * 8;
        const h8 b0 = *(const h8*)&refT[ n16       * RT_LD + kofs];
        const h8 b1 = *(const h8*)&refT[(16 + n16) * RT_LD + kofs];
#pragma unroll
        for (int mi = 0; mi < 4; ++mi) {
            const f4u g0 = pf[ks][mi][0];
            const f4u g1 = pf[ks][mi][1];
            const h8 af = { (_Float16)g0[0], (_Float16)g0[1],
                            (_Float16)g0[2], (_Float16)g0[3],
                            (_Float16)g1[0], (_Float16)g1[1],
                            (_Float16)g1[2], (_Float16)g1[3] };
            acc[mi][0] = __builtin_amdgcn_mfma_f32_16x16x32_f16(af, b0, acc[mi][0], 0, 0, 0);
            acc[mi][1] = __builtin_amdgcn_mfma_f32_16x16x32_f16(af, b1, acc[mi][1], 0, 0, 0);
        }
    }
    // ks PFD..6: R22 scattered dwordx4 path (cols <= 223 < 250, no clamps)
#pragma unroll
    for (int ks = PFD; ks < 7; ++ks) {
        const int kofs = ks * 32 + quad * 8;
        const h8 b0 = *(const h8*)&refT[ n16       * RT_LD + kofs];
        const h8 b1 = *(const h8*)&refT[(16 + n16) * RT_LD + kofs];
#pragma unroll
        for (int mi = 0; mi < 4; ++mi) {
            const f4u g0 = *(const f4u*)(wrow[mi] + kofs);
            const f4u g1 = *(const f4u*)(wrow[mi] + kofs + 4);
            const h8 af = { (_Float16)g0[0], (_Float16)g0[1],
                            (_Float16)g0[2], (_Float16)g0[3],
                            (_Float16)g1[0], (_Float16)g1[1],
                            (_Float16)g1[2], (_Float16)g1[3] };
            acc[mi][0] = __builtin_amdgcn_mfma_f32_16x16x32_f16(af, b0, acc[mi][0], 0, 0, 0);
            acc[mi][1] = __builtin_amdgcn_mfma_f32_16x16x32_f16(af, b1, acc[mi][1], 0, 0, 0);
        }
    }
    { // ks = 7: R12/R22 boundary path verbatim (pair-clamp + zero-select)
        const int kofs = 224 + quad * 8;
        const h8 b0 = *(const h8*)&refT[ n16       * RT_LD + kofs];
        const h8 b1 = *(const h8*)&refT[(16 + n16) * RT_LD + kofs];
#pragma unroll
        for (int mi = 0; mi < 4; ++mi) {
            h8 af;
#pragma unroll
            for (int c = 0; c < 4; ++c) {
                const int col  = kofs + 2 * c;                    // even
                const int colc = (col <= L - 2) ? col : (L - 2);  // pair start <= 248
                const float2 f = *(const float2*)(wrow[mi] + colc); // 8-B aligned
                af[2 * c]     = (_Float16)((col     < L) ? f.x : 0.0f);
                af[2 * c + 1] = (_Float16)((col + 1 < L) ? f.y : 0.0f);
            }
            acc[mi][0] = __builtin_amdgcn_mfma_f32_16x16x32_f16(af, b0, acc[mi][0], 0, 0, 0);
            acc[mi][1] = __builtin_amdgcn_mfma_f32_16x16x32_f16(af, b1, acc[mi][1], 0, 0, 0);
        }
    }

    // ---- Epilogue: D[row=quad*4+r][col=n16] -> out[t][l][a] ---- (R12 verbatim)
    float* outt = out + (size_t)t * (L * A);
#pragma unroll
    for (int mi = 0; mi < 4; ++mi) {
        const int mbase = (w * 4 + mi) * 16 + quad * 4;
#pragma unroll
        for (int nt = 0; nt < 2; ++nt) {
            const int a = nt * 16 + n16;
            if (a < A) {
#pragma unroll
                for (int r = 0; r < 4; ++r) {
                    const int l = mbase + r;
                    if (l < L) outt[l * A + a] = acc[mi][nt][r];
                }
            }
        }
    }
}

extern "C" void kernel_launch(void* const* d_in, const int* in_sizes, int n_in,
                              void* d_out, int out_size, void* d_ws, size_t ws_size,
                              hipStream_t stream) {
    (void)in_sizes; (void)n_in; (void)out_size; (void)d_ws; (void)ws_size;
    const float* vp    = (const float*)d_in[0];
    const float* vs    = (const float*)d_in[1];
    const float* rho   = (const float*)d_in[2];
    const float* theta = (const float*)d_in[3];
    const float* wm    = (const float*)d_in[4];
    float* out = (float*)d_out;

    zoep_fused<<<dim3(T), dim3(256), 0, stream>>>(vp, vs, rho, theta, wm, out);
}

// Round 13
// 99.466 us; speedup vs baseline: 1.1343x; 1.1343x over previous
//
#include <hip/hip_runtime.h>

// Problem constants (from reference)
constexpr int L  = 250;   // layers
constexpr int T  = 600;   // traces
constexpr int A  = 30;    // angles

typedef _Float16 h8  __attribute__((ext_vector_type(8)));   // MFMA A/B frag (4 VGPR)
typedef float    f4  __attribute__((ext_vector_type(4)));   // MFMA C/D frag
// 8-B-aligned float4 (odd wm rows are 1000 B apart); dwordx4 needs 4-B HW align
typedef float    f4u __attribute__((ext_vector_type(4), aligned(8)));

// refT LDS row stride (halfs): 264 = 256+8 -> 16-B aligned rows, 2-way-free banks
constexpr int RT_LD = 264;

// ---------------- R27: R22 (proven best, 41.36 us) + unroll-5 phase-1 --------
// Session ledger (R12..R26): the ONLY passing family is {registers +
// scattered wm loads + refT-LDS written once before one barrier + read-only
// K-loop + plain stores + 256 thr + grid 600}. Closed (correctness): in-loop
// or reused LDS staging (R16/17/19/23/26 - intermittent ghost, even
// straight-line convoys fail the replay check), producer+d_ws (R8-11/21),
// atomics (R24), 512 thr (R14). Closed (performance): angle/M-split write-amp
// or 2x phase-1 tax (R13/R15/R20), monolithic stage LDS->1blk/CU (R18),
// register prefetch VGPR collapse (R25), wider scattered loads flat (R22 vs
// R12). R26 failed the post-468 replay assertion despite first-run absmax
// 0.0039 => staged-with-reuse is unsalvageable here.
//
// R27 re-anchors R22 byte-identical with ONE riskless scheduling delta:
// phase-1 angle loop unroll 2 -> 5 (5 independent solve chains interleaved
// per wave; identical FP ops, identical memory/sync structure). R22 chassis:
// ks<=6 A-frags as 2x dwordx4 (no clamps, cols<=223); ks=7 R12 boundary path.
// NO workspace, NO producer, NO in-loop ds_writes, grid 600 x 256.
__global__ __launch_bounds__(256)
void zoep_fused(const float* __restrict__ vp,
                const float* __restrict__ vs,
                const float* __restrict__ rho,
                const float* __restrict__ theta,
                const float* __restrict__ wm,
                float* __restrict__ out)
{
    __shared__ _Float16 refT[32 * RT_LD];   // 16.5 KB: refT[a][k]
    __shared__ float sth_s[32];
    __shared__ float cth_s[32];

    const int tid = threadIdx.x;
    const int t   = blockIdx.x;

    if (tid < 32) {
        const float th = (tid < A) ? theta[tid] : 0.0f;
        sth_s[tid] = sinf(th);
        cth_s[tid] = cosf(th);
    }
    __syncthreads();

    // ---- Phase 1: thread owns interface k = tid (0..255) ---- (R12 verbatim)
    const int  k     = tid;
    const bool valid = (k < L - 1);
    const int  kc    = valid ? k : (L - 2);   // clamped: loads always in-bounds

    const float a1 = vp[kc * T + t];          // lane-distinct lines, 1 instr/array
    const float a2 = vp[(kc + 1) * T + t];
    const float b1 = vs[kc * T + t];
    const float b2 = vs[(kc + 1) * T + t];
    const float r1 = rho[kc * T + t];
    const float r2 = rho[(kc + 1) * T + t];

    const float ra1  = __builtin_amdgcn_rcpf(a1);
    const float rb1  = r1 * b1, rb2 = r2 * b2;
    const float ra1r = r1 * a1, ra2r = r2 * a2;

#pragma unroll 5
    for (int a = 0; a < A; ++a) {
        const float sth = sth_s[a];           // LDS broadcast (uniform a)
        const float cth = cth_s[a];

        const float p   = sth * ra1;
        const float s2  = p * a2;             // |.| <= 0.84 < 1 (input ranges)
        const float c2  = sqrtf(1.0f - s2 * s2);
        const float sp1 = p * b1;
        const float cp1 = sqrtf(1.0f - sp1 * sp1);
        const float sp2 = p * b2;
        const float cp2 = sqrtf(1.0f - sp2 * sp2);

        const float k1 = 1.0f - 2.0f * sp1 * sp1;
        const float k2 = 1.0f - 2.0f * sp2 * sp2;
        const float q1 = rb1 * k1;
        const float q2 = rb2 * k2;
        const float P1 = ra1r * k1;
        const float P2 = ra2r * k2;
        const float u1 = 2.0f * rb1 * sp1;
        const float u2 = 2.0f * rb2 * sp2;
        const float S1 = u1 * cp1;
        const float S2 = u2 * cp2;
        const float g1 = u1 * cth;
        const float g2 = u2 * c2;

        // M (row-major)
        const float m00 = -sth, m01 = -cp1, m02 = s2,  m03 = cp2;
        const float m10 =  cth, m11 = -sp1, m12 = c2,  m13 = -sp2;
        const float m20 =  g1,  m21 =  q1,  m22 = g2,  m23 = q2;
        const float m30 = -P1,  m31 =  S1,  m32 = P2,  m33 = -S2;

        // 2x2 minors: s* rows{0,1}, c* rows{2,3}
        const float s3v = m01 * m12 - m11 * m02;
        const float s4v = m01 * m13 - m11 * m03;
        const float s5v = m02 * m13 - m12 * m03;
        const float c3v = m21 * m32 - m31 * m22;
        const float c4v = m21 * m33 - m31 * m23;
        const float c5v = m22 * m33 - m32 * m23;
        const float s0v = m00 * m11 - m10 * m01;
        const float s1v = m00 * m12 - m10 * m02;
        const float s2v = m00 * m13 - m10 * m03;
        const float c0v = m20 * m31 - m30 * m21;
        const float c1v = m20 * m32 - m30 * m22;
        const float c2v = m20 * m33 - m30 * m23;

        const float detM = s0v*c5v - s1v*c4v + s2v*c3v
                         + s3v*c2v - s4v*c1v + s5v*c0v;
        const float A0 = m11*c5v - m12*c4v + m13*c3v;   // minor(0,0)
        const float A3 = m21*s5v - m22*s4v + m23*s3v;   // minor(3,0)

        const float num = m00 * A0 - m30 * A3;
        const float res = 1.0f - 2.0f * num * __builtin_amdgcn_rcpf(detM);

        refT[a * RT_LD + k] = (_Float16)(valid ? res : 0.0f);
    }
    // zero pad rows a = 30, 31 (column k)
    refT[30 * RT_LD + k] = (_Float16)0.0f;
    refT[31 * RT_LD + k] = (_Float16)0.0f;
    __syncthreads();

    // ---- Phase 2: MFMA GEMM. wave w owns m-tiles w*4..w*4+3, both n-tiles.
    // Verified layouts (R12): A[m=lane&15][k=quad*8+j], B[k=quad*8+j][n=lane&15],
    // C/D[row=quad*4+reg][col=lane&15].
    const int w    = tid >> 6;       // wave 0..3
    const int lane = tid & 63;
    const int quad = lane >> 4;      // 0..3
    const int n16  = lane & 15;

    f4 acc[4][2];
#pragma unroll
    for (int mi = 0; mi < 4; ++mi)
#pragma unroll
        for (int nt = 0; nt < 2; ++nt) acc[mi][nt] = (f4){0.f, 0.f, 0.f, 0.f};

    // Hoisted, clamped wm row pointers (R15-proven; store-masked at epilogue)
    const float* wrow[4];
#pragma unroll
    for (int mi = 0; mi < 4; ++mi) {
        const int m = (w * 4 + mi) * 16 + n16;        // logical wm row 0..255
        wrow[mi] = wm + ((m < L) ? m : (L - 1)) * L;
    }

    // ks = 0..6: cols kofs..kofs+7 <= 223 < 250 -> no clamps; 2x dwordx4
    // (8-B aligned: row base 0/8 mod 16, kofs multiple of 32 B).
#pragma unroll
    for (int ks = 0; ks < 7; ++ks) {
        const int kofs = ks * 32 + quad * 8;
        const h8 b0 = *(const h8*)&refT[ n16       * RT_LD + kofs];
        const h8 b1 = *(const h8*)&refT[(16 + n16) * RT_LD + kofs];
#pragma unroll
        for (int mi = 0; mi < 4; ++mi) {
            const f4u g0 = *(const f4u*)(wrow[mi] + kofs);
            const f4u g1 = *(const f4u*)(wrow[mi] + kofs + 4);
            const h8 af = { (_Float16)g0[0], (_Float16)g0[1],
                            (_Float16)g0[2], (_Float16)g0[3],
                            (_Float16)g1[0], (_Float16)g1[1],
                            (_Float16)g1[2], (_Float16)g1[3] };
            acc[mi][0] = __builtin_amdgcn_mfma_f32_16x16x32_f16(af, b0, acc[mi][0], 0, 0, 0);
            acc[mi][1] = __builtin_amdgcn_mfma_f32_16x16x32_f16(af, b1, acc[mi][1], 0, 0, 0);
        }
    }
    { // ks = 7: cols 224..255 - only quad==3 (248..255) partial. R12 boundary
      // path verbatim: pair-clamp keeps loads in wm[0..62499], zero-select
      // keeps cols >= 250 finite (they multiply zero refT columns).
        const int kofs = 224 + quad * 8;
        const h8 b0 = *(const h8*)&refT[ n16       * RT_LD + kofs];
        const h8 b1 = *(const h8*)&refT[(16 + n16) * RT_LD + kofs];
#pragma unroll
        for (int mi = 0; mi < 4; ++mi) {
            h8 af;
#pragma unroll
            for (int c = 0; c < 4; ++c) {
                const int col  = kofs + 2 * c;                    // even
                const int colc = (col <= L - 2) ? col : (L - 2);  // pair start <= 248
                const float2 f = *(const float2*)(wrow[mi] + colc); // 8-B aligned
                af[2 * c]     = (_Float16)((col     < L) ? f.x : 0.0f);
                af[2 * c + 1] = (_Float16)((col + 1 < L) ? f.y : 0.0f);
            }
            acc[mi][0] = __builtin_amdgcn_mfma_f32_16x16x32_f16(af, b0, acc[mi][0], 0, 0, 0);
            acc[mi][1] = __builtin_amdgcn_mfma_f32_16x16x32_f16(af, b1, acc[mi][1], 0, 0, 0);
        }
    }

    // ---- Epilogue: D[row=quad*4+r][col=n16] -> out[t][l][a] ---- (R12 verbatim)
    float* outt = out + (size_t)t * (L * A);
#pragma unroll
    for (int mi = 0; mi < 4; ++mi) {
        const int mbase = (w * 4 + mi) * 16 + quad * 4;
#pragma unroll
        for (int nt = 0; nt < 2; ++nt) {
            const int a = nt * 16 + n16;
            if (a < A) {
#pragma unroll
                for (int r = 0; r < 4; ++r) {
                    const int l = mbase + r;
                    if (l < L) outt[l * A + a] = acc[mi][nt][r];
                }
            }
        }
    }
}

extern "C" void kernel_launch(void* const* d_in, const int* in_sizes, int n_in,
                              void* d_out, int out_size, void* d_ws, size_t ws_size,
                              hipStream_t stream) {
    (void)in_sizes; (void)n_in; (void)out_size; (void)d_ws; (void)ws_size;
    const float* vp    = (const float*)d_in[0];
    const float* vs    = (const float*)d_in[1];
    const float* rho   = (const float*)d_in[2];
    const float* theta = (const float*)d_in[3];
    const float* wm    = (const float*)d_in[4];
    float* out = (float*)d_out;

    zoep_fused<<<dim3(T), dim3(256), 0, stream>>>(vp, vs, rho, theta, wm, out);
}

// Round 14
// 95.172 us; speedup vs baseline: 1.1855x; 1.0451x over previous
//
#include <hip/hip_runtime.h>

// Problem constants (from reference)
constexpr int L  = 250;   // layers
constexpr int T  = 600;   // traces
constexpr int A  = 30;    // angles

typedef _Float16 h8  __attribute__((ext_vector_type(8)));   // MFMA A/B frag (4 VGPR)
typedef float    f4  __attribute__((ext_vector_type(4)));   // MFMA C/D frag
// 8-B-aligned float4 (odd wm rows are 1000 B apart); dwordx4 needs 4-B HW align
typedef float    f4u __attribute__((ext_vector_type(4), aligned(8)));

// refT LDS row stride (halfs): 264 = 256+8 -> 16-B aligned rows, 2-way-free banks
constexpr int RT_LD = 264;

// ---------------- R28: R27 chassis + CLOSED-FORM Zoeppritz Rpp ---------------
// Ledger model (R12..R27): dur ~= total_VALU_work / issue_eff. Evidence:
// R15 doubled wm transport -> +2 us (transport ~free); R20 doubled phase-1
// VALU -> +14 us (matches); R18/R25 occupancy cuts -> eff 33% -> +13 us;
// R22 wider loads flat; R27 unroll-5 flat (ILP not limiting). Numerator =
// phase-1's Cramer 4x4 solve (~75 VALU + 4 trans per (k,angle)) is the only
// untouched lever.
//
// R28 replaces the solve with the exact closed-form Rpp (Aki-Richards /
// Dvorkin; bruges zoeppritz_rpp — the documented closed form of the exact
// M/N system the reference builds):
//   m1 = r1(1-2sin^2 phi1), m2 = r2(1-2sin^2 phi2)
//   a = m2-m1, b = m2+2 r1 sin^2 phi1, c = m1+2 r2 sin^2 phi2,
//   d = 2(r2 b2^2 - r1 b1^2)                      [per-k hoisted]
//   C1 = cos(th1)/a1, C2 = cos(th2)/a2, C3 = cos(phi1)/b1, C4 = cos(phi2)/b2
//   E = b C1 + c C2, F = b C3 + c C4, G = a - d C1 C4, H = a - d C2 C3
//   D = E F + G H p^2
//   Rpp = (F (b C1 - c C2) - H p^2 (a + d C1 C4)) / D
// ~38 VALU + 3 sqrt + 1 rcp per angle (was ~75+4): phase-1 VALU halved.
// f32 rearrangement noise (~1e-6) invisible under the f16 GEMM quantization
// that sets the absmax (0.0039 = 2^-8). Phase-2 / epilogue / grid = R27
// byte-identical (proven family: registers + scattered wm + refT write-once
// + read-only K-loop + plain stores + 256 thr + grid 600).
// NO workspace, NO producer, NO in-loop ds_writes.
__global__ __launch_bounds__(256)
void zoep_fused(const float* __restrict__ vp,
                const float* __restrict__ vs,
                const float* __restrict__ rho,
                const float* __restrict__ theta,
                const float* __restrict__ wm,
                float* __restrict__ out)
{
    __shared__ _Float16 refT[32 * RT_LD];   // 16.5 KB: refT[a][k]
    __shared__ float sth_s[32];
    __shared__ float cth_s[32];

    const int tid = threadIdx.x;
    const int t   = blockIdx.x;

    if (tid < 32) {
        const float th = (tid < A) ? theta[tid] : 0.0f;
        sth_s[tid] = sinf(th);
        cth_s[tid] = cosf(th);
    }
    __syncthreads();

    // ---- Phase 1: thread owns interface k = tid (0..255) --------------------
    const int  k     = tid;
    const bool valid = (k < L - 1);
    const int  kc    = valid ? k : (L - 2);   // clamped: loads always in-bounds

    const float a1 = vp[kc * T + t];          // lane-distinct lines, 1 instr/array
    const float a2 = vp[(kc + 1) * T + t];
    const float b1 = vs[kc * T + t];
    const float b2 = vs[(kc + 1) * T + t];
    const float r1 = rho[kc * T + t];
    const float r2 = rho[(kc + 1) * T + t];

    // Per-k hoists (4 trans total; was 1 — negligible)
    const float ra1  = __builtin_amdgcn_rcpf(a1);
    const float ra2  = __builtin_amdgcn_rcpf(a2);
    const float rb1i = __builtin_amdgcn_rcpf(b1);
    const float rb2i = __builtin_amdgcn_rcpf(b2);
    const float b1sq = b1 * b1;
    const float b2sq = b2 * b2;
    const float a2sq = a2 * a2;
    const float dd   = 2.0f * (r2 * b2sq - r1 * b1sq);

#pragma unroll 5
    for (int a = 0; a < A; ++a) {
        const float sth = sth_s[a];           // LDS broadcast (uniform a)
        const float cth = cth_s[a];

        const float p   = sth * ra1;          // ray parameter
        const float p2  = p * p;
        const float x1  = b1sq * p2;          // sin^2 phi1
        const float x2  = b2sq * p2;          // sin^2 phi2
        const float t2  = a2sq * p2;          // sin^2 theta2 (<= 0.71, ranges)
        const float c2  = sqrtf(1.0f - t2);   // cos theta2
        const float cp1 = sqrtf(1.0f - x1);   // cos phi1
        const float cp2 = sqrtf(1.0f - x2);   // cos phi2

        const float m1 = r1 * (1.0f - 2.0f * x1);
        const float m2 = r2 * (1.0f - 2.0f * x2);
        const float av = m2 - m1;
        const float bv = m2 + 2.0f * (r1 * x1);
        const float cv = m1 + 2.0f * (r2 * x2);

        const float C1 = cth * ra1;
        const float C2 = c2  * ra2;
        const float C3 = cp1 * rb1i;
        const float C4 = cp2 * rb2i;

        const float bC1 = bv * C1, cC2 = cv * C2;
        const float bC3 = bv * C3, cC4 = cv * C4;
        const float E   = bC1 + cC2;
        const float F   = bC3 + cC4;
        const float d14 = dd * C1 * C4;
        const float d23 = dd * C2 * C3;
        const float G   = av - d14;
        const float H   = av - d23;
        const float Hp2 = H * p2;
        const float D   = E * F + G * Hp2;
        const float N   = F * (bC1 - cC2) - Hp2 * (av + d14);
        const float res = N * __builtin_amdgcn_rcpf(D);

        refT[a * RT_LD + k] = (_Float16)(valid ? res : 0.0f);
    }
    // zero pad rows a = 30, 31 (column k)
    refT[30 * RT_LD + k] = (_Float16)0.0f;
    refT[31 * RT_LD + k] = (_Float16)0.0f;
    __syncthreads();

    // ---- Phase 2: MFMA GEMM (R27/R22 verbatim) ------------------------------
    // Verified layouts (R12): A[m=lane&15][k=quad*8+j], B[k=quad*8+j][n=lane&15],
    // C/D[row=quad*4+reg][col=lane&15].
    const int w    = tid >> 6;       // wave 0..3
    const int lane = tid & 63;
    const int quad = lane >> 4;      // 0..3
    const int n16  = lane & 15;

    f4 acc[4][2];
#pragma unroll
    for (int mi = 0; mi < 4; ++mi)
#pragma unroll
        for (int nt = 0; nt < 2; ++nt) acc[mi][nt] = (f4){0.f, 0.f, 0.f, 0.f};

    // Hoisted, clamped wm row pointers (R15-proven; store-masked at epilogue)
    const float* wrow[4];
#pragma unroll
    for (int mi = 0; mi < 4; ++mi) {
        const int m = (w * 4 + mi) * 16 + n16;        // logical wm row 0..255
        wrow[mi] = wm + ((m < L) ? m : (L - 1)) * L;
    }

    // ks = 0..6: cols kofs..kofs+7 <= 223 < 250 -> no clamps; 2x dwordx4
#pragma unroll
    for (int ks = 0; ks < 7; ++ks) {
        const int kofs = ks * 32 + quad * 8;
        const h8 b0 = *(const h8*)&refT[ n16       * RT_LD + kofs];
        const h8 b1v = *(const h8*)&refT[(16 + n16) * RT_LD + kofs];
#pragma unroll
        for (int mi = 0; mi < 4; ++mi) {
            const f4u g0 = *(const f4u*)(wrow[mi] + kofs);
            const f4u g1 = *(const f4u*)(wrow[mi] + kofs + 4);
            const h8 af = { (_Float16)g0[0], (_Float16)g0[1],
                            (_Float16)g0[2], (_Float16)g0[3],
                            (_Float16)g1[0], (_Float16)g1[1],
                            (_Float16)g1[2], (_Float16)g1[3] };
            acc[mi][0] = __builtin_amdgcn_mfma_f32_16x16x32_f16(af, b0,  acc[mi][0], 0, 0, 0);
            acc[mi][1] = __builtin_amdgcn_mfma_f32_16x16x32_f16(af, b1v, acc[mi][1], 0, 0, 0);
        }
    }
    { // ks = 7: cols 224..255 - only quad==3 (248..255) partial. R12 boundary
      // path verbatim: pair-clamp keeps loads in wm[0..62499], zero-select
      // keeps cols >= 250 finite (they multiply zero refT columns).
        const int kofs = 224 + quad * 8;
        const h8 b0 = *(const h8*)&refT[ n16       * RT_LD + kofs];
        const h8 b1v = *(const h8*)&refT[(16 + n16) * RT_LD + kofs];
#pragma unroll
        for (int mi = 0; mi < 4; ++mi) {
            h8 af;
#pragma unroll
            for (int c = 0; c < 4; ++c) {
                const int col  = kofs + 2 * c;                    // even
                const int colc = (col <= L - 2) ? col : (L - 2);  // pair start <= 248
                const float2 f = *(const float2*)(wrow[mi] + colc); // 8-B aligned
                af[2 * c]     = (_Float16)((col     < L) ? f.x : 0.0f);
                af[2 * c + 1] = (_Float16)((col + 1 < L) ? f.y : 0.0f);
            }
            acc[mi][0] = __builtin_amdgcn_mfma_f32_16x16x32_f16(af, b0,  acc[mi][0], 0, 0, 0);
            acc[mi][1] = __builtin_amdgcn_mfma_f32_16x16x32_f16(af, b1v, acc[mi][1], 0, 0, 0);
        }
    }

    // ---- Epilogue: D[row=quad*4+r][col=n16] -> out[t][l][a] ---- (R12 verbatim)
    float* outt = out + (size_t)t * (L * A);
#pragma unroll
    for (int mi = 0; mi < 4; ++mi) {
        const int mbase = (w * 4 + mi) * 16 + quad * 4;
#pragma unroll
        for (int nt = 0; nt < 2; ++nt) {
            const int a = nt * 16 + n16;
            if (a < A) {
#pragma unroll
                for (int r = 0; r < 4; ++r) {
                    const int l = mbase + r;
                    if (l < L) outt[l * A + a] = acc[mi][nt][r];
                }
            }
        }
    }
}

extern "C" void kernel_launch(void* const* d_in, const int* in_sizes, int n_in,
                              void* d_out, int out_size, void* d_ws, size_t ws_size,
                              hipStream_t stream) {
    (void)in_sizes; (void)n_in; (void)out_size; (void)d_ws; (void)ws_size;
    const float* vp    = (const float*)d_in[0];
    const float* vs    = (const float*)d_in[1];
    const float* rho   = (const float*)d_in[2];
    const float* theta = (const float*)d_in[3];
    const float* wm    = (const float*)d_in[4];
    float* out = (float*)d_out;

    zoep_fused<<<dim3(T), dim3(256), 0, stream>>>(vp, vs, rho, theta, wm, out);
}